// Round 5
// baseline (308.453 us; speedup 1.0000x reference)
//
#include <hip/hip_runtime.h>
#include <math.h>

#define BB 64
#define EE 512
#define NN 8192
#define MM 64
#define AA 70
#define EPSF 1e-8f
#define RCH 32    // read chunks per batch
#define RR  256   // rows per read block

__device__ __forceinline__ float softplusf(float x) {
    return fmaxf(x, 0.f) + log1pf(expf(-fabsf(x)));
}

// ---------------- K1: addr = emb @ W + b, activations, k_norm ----------------
// Also zeroes the per-batch ticket counters for k_read's fused final reduce.
__global__ __launch_bounds__(576) void k_addr(const float* __restrict__ emb,
                                              const float* __restrict__ W,
                                              const float* __restrict__ bias,
                                              float* __restrict__ ws_k,
                                              float* __restrict__ ws_p,
                                              unsigned* __restrict__ counters) {
    __shared__ float s_emb[EE];
    __shared__ float s_red[8][AA];
    __shared__ float s_addr[AA];
    int b = blockIdx.x;
    int t = threadIdx.x;
    if (t == 0) counters[b] = 0u;   // visible to k_read via dispatch boundary
    for (int i = t; i < EE; i += 576) s_emb[i] = emb[b * EE + i];
    __syncthreads();
    if (t < 560) {
        int seg = t / AA, o = t % AA;
        float acc = 0.f;
        int e0 = seg * 64;
        #pragma unroll 8
        for (int e = e0; e < e0 + 64; ++e) acc += s_emb[e] * W[e * AA + o];
        s_red[seg][o] = acc;
    }
    __syncthreads();
    if (t < AA) {
        float a = bias[t];
        #pragma unroll
        for (int s = 0; s < 8; ++s) a += s_red[s][t];
        s_addr[t] = a;
    }
    __syncthreads();
    if (t < 64) {
        float kv = s_addr[t];
        ws_k[b * 64 + t] = kv;
        float sq = kv * kv;
        for (int off = 32; off > 0; off >>= 1) sq += __shfl_xor(sq, off);
        if (t == 0) {
            float knorm = sqrtf(sq);
            float beta = softplusf(s_addr[64]);
            float g = 1.f / (1.f + expf(-s_addr[65]));
            float s0 = s_addr[66], s1 = s_addr[67], s2 = s_addr[68];
            float mx = fmaxf(s0, fmaxf(s1, s2));
            float e0 = expf(s0 - mx), e1 = expf(s1 - mx), e2 = expf(s2 - mx);
            float es = e0 + e1 + e2;
            float y = 1.f + softplusf(s_addr[69]);
            float* p = ws_p + b * 8;
            p[0] = beta; p[1] = g; p[2] = e0 / es; p[3] = e1 / es; p[4] = e2 / es;
            p[5] = y; p[6] = knorm; p[7] = 0.f;
        }
    }
}

// ---------------- K2: scores = beta * cosine_sim ----------------------------
// 4 lanes per row, each lane owns one 64B quarter-row (4 consecutive float4 =
// one cache line). 2-shuffle reduce. Row loop keeps live set ~45 VGPR so the
// (256,8) bound (<=64 VGPR, 32 waves/CU) holds without spills.
__global__ __launch_bounds__(256, 8) void k_score(const float* __restrict__ mem,
                                                  const float* __restrict__ ws_k,
                                                  const float* __restrict__ ws_p,
                                                  float* __restrict__ out_w) {
    int blk = blockIdx.x;              // BB*64
    int b = blk >> 6;
    int chunk = blk & 63;              // 128 rows per block
    int t = threadIdx.x;
    int q = t & 3;
    int r0 = chunk * 128 + (t >> 2);   // rows r0 and r0+64

    const float4* kq = (const float4*)(ws_k + b * 64 + q * 16);
    float4 k0 = kq[0], k1 = kq[1], k2 = kq[2], k3 = kq[3];
    float beta  = ws_p[b * 8 + 0];
    float knorm = ws_p[b * 8 + 6];

    for (int rr = 0; rr < 2; ++rr) {
        int row = r0 + rr * 64;
        const float4* vp = (const float4*)(mem + ((size_t)(b * NN + row)) * 64 + q * 16);
        float4 v0 = vp[0], v1 = vp[1], v2 = vp[2], v3 = vp[3];
        float dot = v0.x*k0.x + v0.y*k0.y + v0.z*k0.z + v0.w*k0.w
                  + v1.x*k1.x + v1.y*k1.y + v1.z*k1.z + v1.w*k1.w
                  + v2.x*k2.x + v2.y*k2.y + v2.z*k2.z + v2.w*k2.w
                  + v3.x*k3.x + v3.y*k3.y + v3.z*k3.z + v3.w*k3.w;
        float sq  = v0.x*v0.x + v0.y*v0.y + v0.z*v0.z + v0.w*v0.w
                  + v1.x*v1.x + v1.y*v1.y + v1.z*v1.z + v1.w*v1.w
                  + v2.x*v2.x + v2.y*v2.y + v2.z*v2.z + v2.w*v2.w
                  + v3.x*v3.x + v3.y*v3.y + v3.z*v3.z + v3.w*v3.w;
        dot += __shfl_xor(dot, 1); dot += __shfl_xor(dot, 2);
        sq  += __shfl_xor(sq, 1);  sq  += __shfl_xor(sq, 2);
        if (q == 0) {
            float sim = dot / (sqrtf(sq) * knorm + EPSF);
            out_w[(size_t)b * NN + row] = beta * sim;
        }
    }
}

// ---------------- K3: softmax, interpolate, circular conv, sharpen ----------
__device__ __forceinline__ float block_red_max(float v, float* red, int t) {
    int lane = t & 63, wave = t >> 6;
    for (int off = 32; off > 0; off >>= 1) v = fmaxf(v, __shfl_xor(v, off));
    if (lane == 0) red[wave] = v;
    __syncthreads();
    if (t == 0) {
        float r = red[0];
        for (int i = 1; i < 16; ++i) r = fmaxf(r, red[i]);
        red[0] = r;
    }
    __syncthreads();
    float r = red[0];
    __syncthreads();
    return r;
}

__device__ __forceinline__ float block_red_sum(float v, float* red, int t) {
    int lane = t & 63, wave = t >> 6;
    for (int off = 32; off > 0; off >>= 1) v += __shfl_xor(v, off);
    if (lane == 0) red[wave] = v;
    __syncthreads();
    if (t == 0) {
        float r = red[0];
        for (int i = 1; i < 16; ++i) r += red[i];
        red[0] = r;
    }
    __syncthreads();
    float r = red[0];
    __syncthreads();
    return r;
}

__global__ __launch_bounds__(1024) void k_soft(const float* __restrict__ w_prev,
                                               const float* __restrict__ ws_p,
                                               float* __restrict__ out_w) {
    __shared__ float wg[NN];
    __shared__ float red[16];
    int b = blockIdx.x;
    int t = threadIdx.x;
    const float* p = ws_p + b * 8;
    float g = p[1], s0 = p[2], s1 = p[3], s2 = p[4], y = p[5];

    float sc[8];
    float mx = -INFINITY;
    #pragma unroll
    for (int i = 0; i < 8; ++i) {
        sc[i] = out_w[(size_t)b * NN + t + i * 1024];
        mx = fmaxf(mx, sc[i]);
    }
    mx = block_red_max(mx, red, t);

    float e[8]; float lsum = 0.f;
    #pragma unroll
    for (int i = 0; i < 8; ++i) { e[i] = __expf(sc[i] - mx); lsum += e[i]; }
    float tot = block_red_sum(lsum, red, t);
    float inv = 1.f / tot;
    float one_g = 1.f - g;
    #pragma unroll
    for (int i = 0; i < 8; ++i) {
        int n = t + i * 1024;
        float wc = e[i] * inv;
        wg[n] = g * wc + one_g * w_prev[(size_t)b * NN + n];
    }
    __syncthreads();

    float pw[8]; float psum = 0.f;
    #pragma unroll
    for (int i = 0; i < 8; ++i) {
        int n = t + i * 1024;
        float a = wg[(n + NN - 1) & (NN - 1)];
        float c = wg[(n + 1) & (NN - 1)];
        float wsv = s0 * a + s1 * wg[n] + s2 * c;
        // w_s >= 0 always: pow(x,y) = exp2(y*log2(x)); log2(0)=-inf -> 0.
        pw[i] = exp2f(y * __log2f(wsv));
        psum += pw[i];
    }
    float ptot = block_red_sum(psum, red, t);
    float pinv = 1.f / (ptot + EPSF);
    #pragma unroll
    for (int i = 0; i < 8; ++i) {
        int n = t + i * 1024;
        out_w[(size_t)b * NN + n] = pw[i] * pinv;
    }
}

// ---------------- K4: weighted read + fused last-block final reduce ---------
// grid = BB*RCH blocks of 256 threads; RR=256 rows per block. Last arriving
// block per batch (ticket counter) sums the RCH partials in fixed index order
// (bit-deterministic regardless of arrival order).
__global__ __launch_bounds__(256, 8) void k_read(const float* __restrict__ mem,
                                                 const float* __restrict__ out_w,
                                                 float* __restrict__ partials,
                                                 unsigned* __restrict__ counters,
                                                 float* __restrict__ out_md) {
    __shared__ float s_w[RR];
    __shared__ float s_red[16 * 64];
    __shared__ unsigned s_old;
    int blk = blockIdx.x;
    int b = blk >> 5;          // RCH = 32
    int chunk = blk & 31;
    int n0 = chunk * RR;
    int t = threadIdx.x;
    int sub = t & 15, rg = t >> 4;

    s_w[t] = out_w[(size_t)b * NN + n0 + t];
    __syncthreads();

    const float4* memf4 = (const float4*)mem;
    size_t base = ((size_t)b * NN + n0) * 16;
    float ax = 0.f, ay = 0.f, az = 0.f, aw = 0.f;
    #pragma unroll 4
    for (int it = 0; it < RR / 16; ++it) {
        int r = it * 16 + rg;
        float4 v = memf4[base + r * 16 + sub];
        float wv = s_w[r];
        ax += wv * v.x; ay += wv * v.y; az += wv * v.z; aw += wv * v.w;
    }
    float4 acc = {ax, ay, az, aw};
    *(float4*)&s_red[rg * 64 + sub * 4] = acc;
    __syncthreads();
    if (t < 64) {
        float s = 0.f;
        #pragma unroll
        for (int r2 = 0; r2 < 16; ++r2) s += s_red[r2 * 64 + t];
        __hip_atomic_store(&partials[((size_t)b * RCH + chunk) * 64 + t], s,
                           __ATOMIC_RELAXED, __HIP_MEMORY_SCOPE_AGENT);
    }
    __threadfence();           // release partials device-wide
    __syncthreads();
    if (t == 0) {
        s_old = __hip_atomic_fetch_add(&counters[b], 1u,
                                       __ATOMIC_ACQ_REL, __HIP_MEMORY_SCOPE_AGENT);
    }
    __syncthreads();
    if (s_old == RCH - 1 && t < 64) {
        float s = 0.f;
        for (int c = 0; c < RCH; ++c)
            s += __hip_atomic_load(&partials[((size_t)b * RCH + c) * 64 + t],
                                   __ATOMIC_RELAXED, __HIP_MEMORY_SCOPE_AGENT);
        out_md[b * 64 + t] = s;
    }
}

extern "C" void kernel_launch(void* const* d_in, const int* in_sizes, int n_in,
                              void* d_out, int out_size, void* d_ws, size_t ws_size,
                              hipStream_t stream) {
    const float* emb    = (const float*)d_in[0];
    const float* w_prev = (const float*)d_in[1];
    const float* mem    = (const float*)d_in[2];
    const float* W      = (const float*)d_in[3];
    const float* bias   = (const float*)d_in[4];

    float* out    = (float*)d_out;
    float* out_md = out;            // [BB*MM]
    float* out_w  = out + BB * MM;  // [BB*NN]

    float* ws        = (float*)d_ws;
    float* ws_k      = ws;                          // BB*64
    float* ws_p      = ws + BB * 64;                // BB*8
    float* partials  = ws + BB * 64 + BB * 8;       // BB*RCH*64
    unsigned* counters = (unsigned*)(partials + BB * RCH * 64);  // BB

    k_addr <<<BB,       576,  0, stream>>>(emb, W, bias, ws_k, ws_p, counters);
    k_score<<<BB * 64,  256,  0, stream>>>(mem, ws_k, ws_p, out_w);
    k_soft <<<BB,       1024, 0, stream>>>(w_prev, ws_p, out_w);
    k_read <<<BB * RCH, 256,  0, stream>>>(mem, out_w, partials, counters, out_md);
}

// Round 6
// 58.240 us; speedup vs baseline: 5.2962x; 5.2962x over previous
//
#include <hip/hip_runtime.h>
#include <math.h>

#define BB 64
#define EE 512
#define NN 8192
#define MM 64
#define AA 70
#define EPSF 1e-8f

__device__ __forceinline__ float softplusf(float x) {
    return fmaxf(x, 0.f) + log1pf(expf(-fabsf(x)));
}

// ---------------- K1: addr = emb @ W + b, activations, k_norm ----------------
__global__ __launch_bounds__(576) void k_addr(const float* __restrict__ emb,
                                              const float* __restrict__ W,
                                              const float* __restrict__ bias,
                                              float* __restrict__ ws_k,
                                              float* __restrict__ ws_p) {
    __shared__ float s_emb[EE];
    __shared__ float s_red[8][AA];
    __shared__ float s_addr[AA];
    int b = blockIdx.x;
    int t = threadIdx.x;
    for (int i = t; i < EE; i += 576) s_emb[i] = emb[b * EE + i];
    __syncthreads();
    if (t < 560) {
        int seg = t / AA, o = t % AA;
        float acc = 0.f;
        int e0 = seg * 64;
        #pragma unroll 8
        for (int e = e0; e < e0 + 64; ++e) acc += s_emb[e] * W[e * AA + o];
        s_red[seg][o] = acc;
    }
    __syncthreads();
    if (t < AA) {
        float a = bias[t];
        #pragma unroll
        for (int s = 0; s < 8; ++s) a += s_red[s][t];
        s_addr[t] = a;
    }
    __syncthreads();
    if (t < 64) {
        float kv = s_addr[t];
        ws_k[b * 64 + t] = kv;
        float sq = kv * kv;
        for (int off = 32; off > 0; off >>= 1) sq += __shfl_xor(sq, off);
        if (t == 0) {
            float knorm = sqrtf(sq);
            float beta = softplusf(s_addr[64]);
            float g = 1.f / (1.f + expf(-s_addr[65]));
            float s0 = s_addr[66], s1 = s_addr[67], s2 = s_addr[68];
            float mx = fmaxf(s0, fmaxf(s1, s2));
            float e0 = expf(s0 - mx), e1 = expf(s1 - mx), e2 = expf(s2 - mx);
            float es = e0 + e1 + e2;
            float y = 1.f + softplusf(s_addr[69]);
            float* p = ws_p + b * 8;
            p[0] = beta; p[1] = g; p[2] = e0 / es; p[3] = e1 / es; p[4] = e2 / es;
            p[5] = y; p[6] = knorm; p[7] = 0.f;
        }
    }
}

// ---------------- K2: scores = beta * cosine_sim ----------------------------
// 4 lanes per row, each lane owns one 64B quarter-row (one cache line).
// 2-shuffle reduce, no LDS, no barriers. (256,8): 32 waves/CU, no spills.
__global__ __launch_bounds__(256, 8) void k_score(const float* __restrict__ mem,
                                                  const float* __restrict__ ws_k,
                                                  const float* __restrict__ ws_p,
                                                  float* __restrict__ out_w) {
    int blk = blockIdx.x;              // BB*64
    int b = blk >> 6;
    int chunk = blk & 63;              // 128 rows per block
    int t = threadIdx.x;
    int q = t & 3;
    int r0 = chunk * 128 + (t >> 2);   // rows r0 and r0+64

    const float4* kq = (const float4*)(ws_k + b * 64 + q * 16);
    float4 k0 = kq[0], k1 = kq[1], k2 = kq[2], k3 = kq[3];
    float beta  = ws_p[b * 8 + 0];
    float knorm = ws_p[b * 8 + 6];

    for (int rr = 0; rr < 2; ++rr) {
        int row = r0 + rr * 64;
        const float4* vp = (const float4*)(mem + ((size_t)(b * NN + row)) * 64 + q * 16);
        float4 v0 = vp[0], v1 = vp[1], v2 = vp[2], v3 = vp[3];
        float dot = v0.x*k0.x + v0.y*k0.y + v0.z*k0.z + v0.w*k0.w
                  + v1.x*k1.x + v1.y*k1.y + v1.z*k1.z + v1.w*k1.w
                  + v2.x*k2.x + v2.y*k2.y + v2.z*k2.z + v2.w*k2.w
                  + v3.x*k3.x + v3.y*k3.y + v3.z*k3.z + v3.w*k3.w;
        float sq  = v0.x*v0.x + v0.y*v0.y + v0.z*v0.z + v0.w*v0.w
                  + v1.x*v1.x + v1.y*v1.y + v1.z*v1.z + v1.w*v1.w
                  + v2.x*v2.x + v2.y*v2.y + v2.z*v2.z + v2.w*v2.w
                  + v3.x*v3.x + v3.y*v3.y + v3.z*v3.z + v3.w*v3.w;
        dot += __shfl_xor(dot, 1); dot += __shfl_xor(dot, 2);
        sq  += __shfl_xor(sq, 1);  sq  += __shfl_xor(sq, 2);
        if (q == 0) {
            float sim = dot / (sqrtf(sq) * knorm + EPSF);
            out_w[(size_t)b * NN + row] = beta * sim;
        }
    }
}

// ---------------- K3: softmax, interpolate, circular conv, sharpen ----------
__device__ __forceinline__ float block_red_max(float v, float* red, int t) {
    int lane = t & 63, wave = t >> 6;
    for (int off = 32; off > 0; off >>= 1) v = fmaxf(v, __shfl_xor(v, off));
    if (lane == 0) red[wave] = v;
    __syncthreads();
    if (t == 0) {
        float r = red[0];
        for (int i = 1; i < 16; ++i) r = fmaxf(r, red[i]);
        red[0] = r;
    }
    __syncthreads();
    float r = red[0];
    __syncthreads();
    return r;
}

__device__ __forceinline__ float block_red_sum(float v, float* red, int t) {
    int lane = t & 63, wave = t >> 6;
    for (int off = 32; off > 0; off >>= 1) v += __shfl_xor(v, off);
    if (lane == 0) red[wave] = v;
    __syncthreads();
    if (t == 0) {
        float r = red[0];
        for (int i = 1; i < 16; ++i) r += red[i];
        red[0] = r;
    }
    __syncthreads();
    float r = red[0];
    __syncthreads();
    return r;
}

__global__ __launch_bounds__(1024) void k_soft(const float* __restrict__ w_prev,
                                               const float* __restrict__ ws_p,
                                               float* __restrict__ out_w) {
    __shared__ float wg[NN];
    __shared__ float red[16];
    int b = blockIdx.x;
    int t = threadIdx.x;
    const float* p = ws_p + b * 8;
    float g = p[1], s0 = p[2], s1 = p[3], s2 = p[4], y = p[5];

    float sc[8];
    float mx = -INFINITY;
    #pragma unroll
    for (int i = 0; i < 8; ++i) {
        sc[i] = out_w[(size_t)b * NN + t + i * 1024];
        mx = fmaxf(mx, sc[i]);
    }
    mx = block_red_max(mx, red, t);

    float e[8]; float lsum = 0.f;
    #pragma unroll
    for (int i = 0; i < 8; ++i) { e[i] = __expf(sc[i] - mx); lsum += e[i]; }
    float tot = block_red_sum(lsum, red, t);
    float inv = 1.f / tot;
    float one_g = 1.f - g;
    #pragma unroll
    for (int i = 0; i < 8; ++i) {
        int n = t + i * 1024;
        float wc = e[i] * inv;
        wg[n] = g * wc + one_g * w_prev[(size_t)b * NN + n];
    }
    __syncthreads();

    float pw[8]; float psum = 0.f;
    #pragma unroll
    for (int i = 0; i < 8; ++i) {
        int n = t + i * 1024;
        float a = wg[(n + NN - 1) & (NN - 1)];
        float c = wg[(n + 1) & (NN - 1)];
        float wsv = s0 * a + s1 * wg[n] + s2 * c;
        // w_s >= 0 always: pow(x,y) = exp2(y*log2(x)); log2(0)=-inf -> 0.
        pw[i] = exp2f(y * __log2f(wsv));
        psum += pw[i];
    }
    float ptot = block_red_sum(psum, red, t);
    float pinv = 1.f / (ptot + EPSF);
    #pragma unroll
    for (int i = 0; i < 8; ++i) {
        int n = t + i * 1024;
        out_w[(size_t)b * NN + n] = pw[i] * pinv;
    }
}

// ---------------- K4: weighted read partials (float4, LDS reduce) -----------
// grid = BB*16 blocks of 256 threads; 512 rows per block. Plain stores,
// separate final-reduce kernel (device fences in the streamer were a 14x
// regression in round 5 — never again).
#define RR 512
__global__ __launch_bounds__(256) void k_read(const float* __restrict__ mem,
                                              const float* __restrict__ out_w,
                                              float* __restrict__ partials) {
    __shared__ float s_w[RR];
    __shared__ float s_red[16 * 64];
    int blk = blockIdx.x;
    int b = blk >> 4;
    int chunk = blk & 15;
    int n0 = chunk * RR;
    int t = threadIdx.x;
    int sub = t & 15, rg = t >> 4;

    for (int i = t; i < RR; i += 256) s_w[i] = out_w[(size_t)b * NN + n0 + i];
    __syncthreads();

    const float4* memf4 = (const float4*)mem;
    size_t base = ((size_t)b * NN + n0) * 16;
    float ax = 0.f, ay = 0.f, az = 0.f, aw = 0.f;
    #pragma unroll 4
    for (int it = 0; it < RR / 16; ++it) {
        int r = it * 16 + rg;
        float4 v = memf4[base + r * 16 + sub];
        float wv = s_w[r];
        ax += wv * v.x; ay += wv * v.y; az += wv * v.z; aw += wv * v.w;
    }
    float4 acc = {ax, ay, az, aw};
    *(float4*)&s_red[rg * 64 + sub * 4] = acc;
    __syncthreads();
    if (t < 64) {
        float s = 0.f;
        #pragma unroll
        for (int r2 = 0; r2 < 16; ++r2) s += s_red[r2 * 64 + t];
        partials[((size_t)b * 16 + chunk) * 64 + t] = s;
    }
}

__global__ void k_final(const float* __restrict__ partials, float* __restrict__ out_md) {
    int b = blockIdx.x;
    int m = threadIdx.x; // 64
    float s = 0.f;
    #pragma unroll
    for (int c = 0; c < 16; ++c) s += partials[((size_t)b * 16 + c) * 64 + m];
    out_md[b * 64 + m] = s;
}

extern "C" void kernel_launch(void* const* d_in, const int* in_sizes, int n_in,
                              void* d_out, int out_size, void* d_ws, size_t ws_size,
                              hipStream_t stream) {
    const float* emb    = (const float*)d_in[0];
    const float* w_prev = (const float*)d_in[1];
    const float* mem    = (const float*)d_in[2];
    const float* W      = (const float*)d_in[3];
    const float* bias   = (const float*)d_in[4];

    float* out    = (float*)d_out;
    float* out_md = out;            // [BB*MM]
    float* out_w  = out + BB * MM;  // [BB*NN]

    float* ws       = (float*)d_ws;
    float* ws_k     = ws;                       // BB*64
    float* ws_p     = ws + BB * 64;             // BB*8
    float* partials = ws + BB * 64 + BB * 8;    // BB*16*64

    k_addr <<<BB,      576,  0, stream>>>(emb, W, bias, ws_k, ws_p);
    k_score<<<BB * 64, 256,  0, stream>>>(mem, ws_k, ws_p, out_w);
    k_soft <<<BB,      1024, 0, stream>>>(w_prev, ws_p, out_w);
    k_read <<<BB * 16, 256,  0, stream>>>(mem, out_w, partials);
    k_final<<<BB,      64,   0, stream>>>(partials, out_md);
}

// Round 7
// 56.392 us; speedup vs baseline: 5.4698x; 1.0328x over previous
//
#include <hip/hip_runtime.h>
#include <math.h>

#define BB 64
#define EE 512
#define NN 8192
#define MM 64
#define AA 70
#define EPSF 1e-8f

__device__ __forceinline__ float softplusf(float x) {
    return fmaxf(x, 0.f) + log1pf(expf(-fabsf(x)));
}

// ---------------- K1: addr = emb @ W + b, activations, k_norm ----------------
__global__ __launch_bounds__(576) void k_addr(const float* __restrict__ emb,
                                              const float* __restrict__ W,
                                              const float* __restrict__ bias,
                                              float* __restrict__ ws_k,
                                              float* __restrict__ ws_p) {
    __shared__ float s_emb[EE];
    __shared__ float s_red[8][AA];
    __shared__ float s_addr[AA];
    int b = blockIdx.x;
    int t = threadIdx.x;
    for (int i = t; i < EE; i += 576) s_emb[i] = emb[b * EE + i];
    __syncthreads();
    if (t < 560) {
        int seg = t / AA, o = t % AA;
        float acc = 0.f;
        int e0 = seg * 64;
        #pragma unroll 8
        for (int e = e0; e < e0 + 64; ++e) acc += s_emb[e] * W[e * AA + o];
        s_red[seg][o] = acc;
    }
    __syncthreads();
    if (t < AA) {
        float a = bias[t];
        #pragma unroll
        for (int s = 0; s < 8; ++s) a += s_red[s][t];
        s_addr[t] = a;
    }
    __syncthreads();
    if (t < 64) {
        float kv = s_addr[t];
        ws_k[b * 64 + t] = kv;
        float sq = kv * kv;
        for (int off = 32; off > 0; off >>= 1) sq += __shfl_xor(sq, off);
        if (t == 0) {
            float knorm = sqrtf(sq);
            float beta = softplusf(s_addr[64]);
            float g = 1.f / (1.f + expf(-s_addr[65]));
            float s0 = s_addr[66], s1 = s_addr[67], s2 = s_addr[68];
            float mx = fmaxf(s0, fmaxf(s1, s2));
            float e0 = expf(s0 - mx), e1 = expf(s1 - mx), e2 = expf(s2 - mx);
            float es = e0 + e1 + e2;
            float y = 1.f + softplusf(s_addr[69]);
            float* p = ws_p + b * 8;
            p[0] = beta; p[1] = g; p[2] = e0 / es; p[3] = e1 / es; p[4] = e2 / es;
            p[5] = y; p[6] = knorm; p[7] = 0.f;
        }
    }
}

// ---------------- K2: scores = beta * cosine_sim ----------------------------
// 4 lanes per row, each lane owns one 64B quarter-row (one cache line).
// 2-shuffle reduce, no LDS/barriers. 4 rows per thread amortizes the block
// prologue; loop is barrier-free so loads pipeline across iterations.
__global__ __launch_bounds__(256, 8) void k_score(const float* __restrict__ mem,
                                                  const float* __restrict__ ws_k,
                                                  const float* __restrict__ ws_p,
                                                  float* __restrict__ out_w) {
    int blk = blockIdx.x;              // BB*32
    int b = blk >> 5;
    int chunk = blk & 31;              // 256 rows per block
    int t = threadIdx.x;
    int q = t & 3;
    int r0 = chunk * 256 + (t >> 2);   // rows r0 + {0,64,128,192}

    const float4* kq = (const float4*)(ws_k + b * 64 + q * 16);
    float4 k0 = kq[0], k1 = kq[1], k2 = kq[2], k3 = kq[3];
    float beta  = ws_p[b * 8 + 0];
    float knorm = ws_p[b * 8 + 6];

    for (int rr = 0; rr < 4; ++rr) {
        int row = r0 + rr * 64;
        const float4* vp = (const float4*)(mem + ((size_t)(b * NN + row)) * 64 + q * 16);
        float4 v0 = vp[0], v1 = vp[1], v2 = vp[2], v3 = vp[3];
        float dot = v0.x*k0.x + v0.y*k0.y + v0.z*k0.z + v0.w*k0.w
                  + v1.x*k1.x + v1.y*k1.y + v1.z*k1.z + v1.w*k1.w
                  + v2.x*k2.x + v2.y*k2.y + v2.z*k2.z + v2.w*k2.w
                  + v3.x*k3.x + v3.y*k3.y + v3.z*k3.z + v3.w*k3.w;
        float sq  = v0.x*v0.x + v0.y*v0.y + v0.z*v0.z + v0.w*v0.w
                  + v1.x*v1.x + v1.y*v1.y + v1.z*v1.z + v1.w*v1.w
                  + v2.x*v2.x + v2.y*v2.y + v2.z*v2.z + v2.w*v2.w
                  + v3.x*v3.x + v3.y*v3.y + v3.z*v3.z + v3.w*v3.w;
        dot += __shfl_xor(dot, 1); dot += __shfl_xor(dot, 2);
        sq  += __shfl_xor(sq, 1);  sq  += __shfl_xor(sq, 2);
        if (q == 0) {
            float sim = dot / (sqrtf(sq) * knorm + EPSF);
            out_w[(size_t)b * NN + row] = beta * sim;
        }
    }
}

// ---------------- K3: softmax, interpolate, circular conv, sharpen ----------
// Also zeroes out_md (runs entirely before k_read in stream order).
__device__ __forceinline__ float block_red_max(float v, float* red, int t) {
    int lane = t & 63, wave = t >> 6;
    for (int off = 32; off > 0; off >>= 1) v = fmaxf(v, __shfl_xor(v, off));
    if (lane == 0) red[wave] = v;
    __syncthreads();
    if (t == 0) {
        float r = red[0];
        for (int i = 1; i < 16; ++i) r = fmaxf(r, red[i]);
        red[0] = r;
    }
    __syncthreads();
    float r = red[0];
    __syncthreads();
    return r;
}

__device__ __forceinline__ float block_red_sum(float v, float* red, int t) {
    int lane = t & 63, wave = t >> 6;
    for (int off = 32; off > 0; off >>= 1) v += __shfl_xor(v, off);
    if (lane == 0) red[wave] = v;
    __syncthreads();
    if (t == 0) {
        float r = red[0];
        for (int i = 1; i < 16; ++i) r += red[i];
        red[0] = r;
    }
    __syncthreads();
    float r = red[0];
    __syncthreads();
    return r;
}

__global__ __launch_bounds__(1024) void k_soft(const float* __restrict__ w_prev,
                                               const float* __restrict__ ws_p,
                                               float* __restrict__ out_w,
                                               float* __restrict__ out_md) {
    __shared__ float wg[NN];
    __shared__ float red[16];
    int b = blockIdx.x;
    int t = threadIdx.x;
    if (t < 64) out_md[b * 64 + t] = 0.f;   // init for k_read's atomicAdd
    const float* p = ws_p + b * 8;
    float g = p[1], s0 = p[2], s1 = p[3], s2 = p[4], y = p[5];

    float sc[8];
    float mx = -INFINITY;
    #pragma unroll
    for (int i = 0; i < 8; ++i) {
        sc[i] = out_w[(size_t)b * NN + t + i * 1024];
        mx = fmaxf(mx, sc[i]);
    }
    mx = block_red_max(mx, red, t);

    float e[8]; float lsum = 0.f;
    #pragma unroll
    for (int i = 0; i < 8; ++i) { e[i] = __expf(sc[i] - mx); lsum += e[i]; }
    float tot = block_red_sum(lsum, red, t);
    float inv = 1.f / tot;
    float one_g = 1.f - g;
    #pragma unroll
    for (int i = 0; i < 8; ++i) {
        int n = t + i * 1024;
        float wc = e[i] * inv;
        wg[n] = g * wc + one_g * w_prev[(size_t)b * NN + n];
    }
    __syncthreads();

    float pw[8]; float psum = 0.f;
    #pragma unroll
    for (int i = 0; i < 8; ++i) {
        int n = t + i * 1024;
        float a = wg[(n + NN - 1) & (NN - 1)];
        float c = wg[(n + 1) & (NN - 1)];
        float wsv = s0 * a + s1 * wg[n] + s2 * c;
        // w_s >= 0 always: pow(x,y) = exp2(y*log2(x)); log2(0)=-inf -> 0.
        pw[i] = exp2f(y * __log2f(wsv));
        psum += pw[i];
    }
    float ptot = block_red_sum(psum, red, t);
    float pinv = 1.f / (ptot + EPSF);
    #pragma unroll
    for (int i = 0; i < 8; ++i) {
        int n = t + i * 1024;
        out_w[(size_t)b * NN + n] = pw[i] * pinv;
    }
}

// ---------------- K4: weighted read, atomicAdd into out_md ------------------
// grid = BB*16 blocks of 256 threads; 512 rows per block. Plain VMEM atomics,
// NO fences/tickets (round-5 lesson). 16 adders per output address; order
// variation ~1e-6, far under threshold.
#define RR 512
__global__ __launch_bounds__(256) void k_read(const float* __restrict__ mem,
                                              const float* __restrict__ out_w,
                                              float* __restrict__ out_md) {
    __shared__ float s_w[RR];
    __shared__ float s_red[16 * 64];
    int blk = blockIdx.x;
    int b = blk >> 4;
    int chunk = blk & 15;
    int n0 = chunk * RR;
    int t = threadIdx.x;
    int sub = t & 15, rg = t >> 4;

    for (int i = t; i < RR; i += 256) s_w[i] = out_w[(size_t)b * NN + n0 + i];
    __syncthreads();

    const float4* memf4 = (const float4*)mem;
    size_t base = ((size_t)b * NN + n0) * 16;
    float ax = 0.f, ay = 0.f, az = 0.f, aw = 0.f;
    #pragma unroll 8
    for (int it = 0; it < RR / 16; ++it) {
        int r = it * 16 + rg;
        float4 v = memf4[base + r * 16 + sub];
        float wv = s_w[r];
        ax += wv * v.x; ay += wv * v.y; az += wv * v.z; aw += wv * v.w;
    }
    float4 acc = {ax, ay, az, aw};
    *(float4*)&s_red[rg * 64 + sub * 4] = acc;
    __syncthreads();
    if (t < 64) {
        float s = 0.f;
        #pragma unroll
        for (int r2 = 0; r2 < 16; ++r2) s += s_red[r2 * 64 + t];
        atomicAdd(&out_md[b * 64 + t], s);
    }
}

extern "C" void kernel_launch(void* const* d_in, const int* in_sizes, int n_in,
                              void* d_out, int out_size, void* d_ws, size_t ws_size,
                              hipStream_t stream) {
    const float* emb    = (const float*)d_in[0];
    const float* w_prev = (const float*)d_in[1];
    const float* mem    = (const float*)d_in[2];
    const float* W      = (const float*)d_in[3];
    const float* bias   = (const float*)d_in[4];

    float* out    = (float*)d_out;
    float* out_md = out;            // [BB*MM]
    float* out_w  = out + BB * MM;  // [BB*NN]

    float* ws   = (float*)d_ws;
    float* ws_k = ws;               // BB*64
    float* ws_p = ws + BB * 64;     // BB*8

    k_addr <<<BB,      576,  0, stream>>>(emb, W, bias, ws_k, ws_p);
    k_score<<<BB * 32, 256,  0, stream>>>(mem, ws_k, ws_p, out_w);
    k_soft <<<BB,      1024, 0, stream>>>(w_prev, ws_p, out_w, out_md);
    k_read <<<BB * 16, 256,  0, stream>>>(mem, out_w, out_md);
}